// Round 20
// baseline (164.463 us; speedup 1.0000x reference)
//
#include <hip/hip_runtime.h>
#include <stdint.h>

// RoPE attention, MI355X. S=4096, HID=1024, 16 heads x 64.
// R20: attn identical to R18/R19 (fragment-linear K/V, 98.5us stable). Non-attn
// fixes: (1) K epilogue writes rotated K into LDS [128][128] bf16 (swizzled),
// then 8 fully-coalesced 16B KF stores/thread (replaces 64 scattered 2B stores);
// (2) interleaved (cos,sin) float2 table halves epilogue gathers; (3) convert +
// table fused into one kernel (one less dispatch).
// ws layout: qbf 8MB | KF 8MB | VF 8MB | xbf 8MB | wbf 6MB | ctst 1MB

#define SEQLEN 4096
#define NHEAD 16
#define HDIM 64

typedef __bf16 bf16x8 __attribute__((ext_vector_type(8)));
typedef float f32x4 __attribute__((ext_vector_type(4)));
typedef float f32x16 __attribute__((ext_vector_type(16)));

__device__ __forceinline__ unsigned short f2bf(float f) {
  union { float f; unsigned int u; } v; v.f = f;
  unsigned int r = v.u + 0x7FFFu + ((v.u >> 16) & 1u);
  return (unsigned short)(r >> 16);
}
__device__ __forceinline__ unsigned int pkc(float lo, float hi) {
  union { __bf16 b[2]; unsigned int u; } z;
  z.b[0] = (__bf16)lo; z.b[1] = (__bf16)hi;
  return z.u;
}
__device__ __forceinline__ bf16x8 as_bf(uint4 v) { return __builtin_bit_cast(bf16x8, v); }
__device__ __forceinline__ f32x4 mfma16(bf16x8 a, bf16x8 b, f32x4 c) {
  return __builtin_amdgcn_mfma_f32_16x16x32_bf16(a, b, c, 0, 0, 0);
}
__device__ __forceinline__ f32x16 mfma32(bf16x8 a, bf16x8 b, f32x16 c) {
  return __builtin_amdgcn_mfma_f32_32x32x16_bf16(a, b, c, 0, 0, 0);
}
__device__ __forceinline__ void gll16(const void* g, void* l) {
  __builtin_amdgcn_global_load_lds(
      (const __attribute__((address_space(1))) void*)g,
      (__attribute__((address_space(3))) void*)l, 16, 0, 0);
}

// ---------------- prep: fp32->bf16 convert (x, wq|wk|wv) + RoPE float2 table ----
__global__ __launch_bounds__(256) void k_prep(
    const float* __restrict__ x, const float* __restrict__ wq,
    const float* __restrict__ wk, const float* __restrict__ wv,
    unsigned short* __restrict__ xbf, unsigned short* __restrict__ wbf,
    float2* __restrict__ ctst) {
  const int NX = SEQLEN * 1024 / 4;         // 1048576 float4s
  const int NW = 1024 * 1024 / 4;           // 262144 (pow2)
  if (blockIdx.x < 7168) {
    int i = blockIdx.x * 256 + threadIdx.x;
    float4 v;
    unsigned short* dst;
    int di;
    if (i < NX) {
      v = ((const float4*)x)[i]; dst = xbf; di = i;
    } else {
      int j = i - NX;
      const float4* src = (const float4*)((j < NW) ? wq : (j < 2 * NW) ? wk : wv);
      v = src[j & (NW - 1)];
      dst = wbf; di = j;
    }
    ushort4 o; o.x = f2bf(v.x); o.y = f2bf(v.y); o.z = f2bf(v.z); o.w = f2bf(v.w);
    ((ushort4*)dst)[di] = o;
  } else {
    int i = (blockIdx.x - 7168) * 256 + threadIdx.x;   // 4096*32 entries
    int s = i >> 5, j = i & 31;
    double inv = exp(-(double)j * 0.28782313662425572);  // ln(10000)/32
    double a = (double)s * inv;
    float2 cs; cs.x = (float)cos(a); cs.y = (float)sin(a);
    ctst[i] = cs;
  }
}

// ---------------- QKV GEMM (gll16 staging + RoPE epilogue; K via LDS transpose) ----
__global__ __launch_bounds__(256) void k_gemm(
    const unsigned short* __restrict__ xbf, const unsigned short* __restrict__ wbf,
    const float2* __restrict__ ctst,
    unsigned short* __restrict__ qbf, unsigned short* __restrict__ KF,
    unsigned short* __restrict__ VF) {
  __shared__ __align__(16) char lds[32768];  // As[2] 8KB | Bs[2] 8KB ; reused as TB
  const int t = threadIdx.x;
  const int bn = blockIdx.x, bm = blockIdx.y;
  const int lane = t & 63, wave = t >> 6;
  const int r = lane & 15, g = lane >> 4;
  const int wm = wave >> 1, wn = wave & 1;

  // staging chunks: wave w covers rows [32w..32w+32); 4 lanes per 64B row
  const int c0 = 2 * wave, c1 = 2 * wave + 1;
  const int srowA = lane >> 2, sb = (lane & 3) * 16;
  const char* gA0 = (const char*)xbf + (size_t)(bm * 128 + 16 * c0 + srowA) * 2048 + sb;
  const char* gA1 = (const char*)xbf + (size_t)(bm * 128 + 16 * c1 + srowA) * 2048 + sb;
  const char* gB0 = (const char*)wbf + (size_t)(bn * 128 + 16 * c0 + srowA) * 2048 + sb;
  const char* gB1 = (const char*)wbf + (size_t)(bn * 128 + 16 * c1 + srowA) * 2048 + sb;

  // prologue: tile 0 -> buffer 0
  gll16(gA0, lds + c0 * 1024);
  gll16(gA1, lds + c1 * 1024);
  gll16(gB0, lds + 16384 + c0 * 1024);
  gll16(gB1, lds + 16384 + c1 * 1024);
  gA0 += 64; gA1 += 64; gB0 += 64; gB1 += 64;

  f32x4 zero4 = {0.f, 0.f, 0.f, 0.f};
  f32x4 acc[4][4];
#pragma unroll
  for (int m = 0; m < 4; ++m)
#pragma unroll
    for (int n = 0; n < 4; ++n) acc[m][n] = zero4;

  for (int kk = 0; kk < 32; ++kk) {
    __syncthreads();   // drains tile-kk loads + prior LDS reads
    if (kk < 31) {
      char* Ad = lds + ((kk + 1) & 1) * 8192;
      char* Bd = lds + 16384 + ((kk + 1) & 1) * 8192;
      gll16(gA0, Ad + c0 * 1024);
      gll16(gA1, Ad + c1 * 1024);
      gll16(gB0, Bd + c0 * 1024);
      gll16(gB1, Bd + c1 * 1024);
      gA0 += 64; gA1 += 64; gB0 += 64; gB1 += 64;
    }
    const char* Ac = lds + (kk & 1) * 8192;
    const char* Bc = lds + 16384 + (kk & 1) * 8192;
    bf16x8 af[4], bfr[4];
#pragma unroll
    for (int m = 0; m < 4; ++m)
      af[m] = as_bf(*(const uint4*)(Ac + (wm * 64 + m * 16 + r) * 64 + g * 16));
#pragma unroll
    for (int n = 0; n < 4; ++n)
      bfr[n] = as_bf(*(const uint4*)(Bc + (wn * 64 + n * 16 + r) * 64 + g * 16));
#pragma unroll
    for (int m = 0; m < 4; ++m)
#pragma unroll
      for (int n = 0; n < 4; ++n)
        acc[m][n] = mfma16(af[m], bfr[n], acc[m][n]);
  }

  // Epilogue. C/D layout: col = lane&15 (=r), row = 4*g + reg.
  const int matid = bn >> 3;  // 0=q, 1=k, 2=v
  if (matid == 1) {
    // ---- K: RoPE into LDS [128 key][128 col] bf16 (swizzled 16B slots) ----
    __syncthreads();
#pragma unroll
    for (int m = 0; m < 4; ++m) {
      const int rl0 = wm * 64 + m * 16 + 4 * g;
#pragma unroll
      for (int n = 0; n < 4; ++n) {
        const int cl = wn * 64 + n * 16 + r;
        const int jdx = (cl >> 1) & 31;
        const float sgn = (cl & 1) ? 1.0f : -1.0f;
#pragma unroll
        for (int j = 0; j < 4; ++j) {
          float v = acc[m][n][j];
          float p = __shfl_xor(v, 1);  // RoPE pair partner
          const int rl = rl0 + j;
          float2 cs = ctst[(bm * 128 + rl) * 32 + jdx];
          float o = v * cs.x + p * cs.y * sgn;
          const int byte = rl * 256 + ((2 * cl) ^ ((rl & 15) << 4));
          *(unsigned short*)(lds + byte) = f2bf(o);
        }
      }
    }
    __syncthreads();
    // ---- coalesced KF stores: 8 x 16B per thread, 1KB/wave-instr ----
#pragma unroll
    for (int it = 0; it < 8; ++it) {
      const int e = it * 256 + t;               // (h2,ktl,c,ln)
      const int h2 = e >> 10, ktl = (e >> 8) & 3, c = (e >> 6) & 3, ln = e & 63;
      const int row = ktl * 32 + (ln & 31);
      const int col = h2 * 64 + c * 16 + (ln >> 5) * 8;
      uint4 v = *(const uint4*)(lds + row * 256 + ((2 * col) ^ ((row & 15) << 4)));
      size_t off = (size_t)((bn - 8) * 2 + h2) * 524288 +
                   (size_t)(bm * 4 + ktl) * 4096 + (size_t)c * 1024 + (size_t)ln * 16;
      *(uint4*)((char*)KF + off) = v;
    }
  } else {
#pragma unroll
    for (int m = 0; m < 4; ++m) {
      const int row0 = bm * 128 + wm * 64 + m * 16 + 4 * g;
#pragma unroll
      for (int n = 0; n < 4; ++n) {
        const int col = bn * 128 + wn * 64 + n * 16 + r;
        const int d = col & 63;
        const int hh = (col >> 6) & 15;
        if (matid == 0) {
          const int jdx = (col >> 1) & 31;
          const float sgn = (col & 1) ? 1.0f : -1.0f;
          const float qs = 0.18033688011112042f;  // (1/8)*log2(e)
#pragma unroll
          for (int j = 0; j < 4; ++j) {
            float v = acc[m][n][j];
            float p = __shfl_xor(v, 1);
            int srow = row0 + j;
            float2 cs = ctst[srow * 32 + jdx];
            float o = (v * cs.x + p * cs.y * sgn) * qs;
            qbf[(size_t)srow * 1024 + (hh * 64 + d)] = f2bf(o);
          }
        } else {
          // VF[h][kt][dt][kc][lane][16B]: b64 = keys row0..row0+3 at this d.
          ushort4 o;
          o.x = f2bf(acc[m][n][0]); o.y = f2bf(acc[m][n][1]);
          o.z = f2bf(acc[m][n][2]); o.w = f2bf(acc[m][n][3]);
          const int kt = row0 >> 5, q4 = (row0 >> 2) & 7;
          const int kc = q4 >> 2, bb = (q4 >> 1) & 1, h2v = q4 & 1;
          const int dt = d >> 5, l2 = d & 31;
          size_t off = (size_t)hh * 524288 + (size_t)kt * 4096 + (size_t)dt * 2048 +
                       (size_t)kc * 1024 + (size_t)(h2v * 32 + l2) * 16 + bb * 8;
          *(ushort4*)((char*)VF + off) = o;
        }
      }
    }
  }
}

// ---------------- Flash attention (fragment-linear K/V, barrier-free loop,
//                  wave-staggered tile order) -- identical to R18 ----
__global__ __launch_bounds__(512) void k_attn(
    const unsigned short* __restrict__ qbf, const unsigned short* __restrict__ KF,
    const unsigned short* __restrict__ VF, float* __restrict__ out) {
  __shared__ __align__(16) char smem[33280];
  const int t = threadIdx.x;
  // XCD swizzle: 512 blocks, 8 XCDs, 64 blocks/XCD -> 2 heads per XCD
  const int b = blockIdx.x;
  const int work = (b & 7) * 64 + (b >> 3);
  const int h = work >> 5;
  const int qb = work & 31;
  const int lane = t & 63, wave = t >> 6;
  const int qw = wave & 3, hf = wave >> 2;
  const int li = lane & 31, hi = lane >> 5;
  const int q0 = qb * 128 + qw * 32;

  // Q fragments (B-operand): lane holds q = q0+li, d = c*16 + hi*8 + j. Pre-scaled.
  bf16x8 qf[4];
#pragma unroll
  for (int c = 0; c < 4; ++c)
    qf[c] = as_bf(*(const uint4*)((const char*)qbf +
              (size_t)(q0 + li) * 2048 + h * 128 + c * 32 + hi * 16));

  f32x16 z16 = {0.f};
  f32x16 acc[2];            // O^T accum: d-tile dt, row=d, col=q
  acc[0] = z16; acc[1] = z16;
  float l4[4] = {0.f, 0.f, 0.f, 0.f};

  // fragment-linear base pointers (16B/lane, contiguous per wave)
  const char* pK = (const char*)KF + (size_t)h * 524288 + (size_t)hf * 262144 + lane * 16;
  const char* pV = (const char*)VF + (size_t)h * 524288 + (size_t)hf * 262144 + lane * 16;

  const int start = wave * 8;   // stagger: 0,8,16,...,56

  for (int jj = 0; jj < 64; ++jj) {
    const int j = (start + jj) & 63;
    const char* tK = pK + ((size_t)j << 12);
    const char* tV = pV + ((size_t)j << 12);
    // ---- K fragments: 4 coalesced 1KB loads ----
    bf16x8 kf[4];
#pragma unroll
    for (int c = 0; c < 4; ++c)
      kf[c] = as_bf(*(const uint4*)(tK + c * 1024));
    // ---- V fragments: 4 coalesced 1KB loads ----
    bf16x8 vf2[2][2];
#pragma unroll
    for (int dt = 0; dt < 2; ++dt)
#pragma unroll
      for (int kc = 0; kc < 2; ++kc)
        vf2[dt][kc] = as_bf(*(const uint4*)(tV + dt * 2048 + kc * 1024));

    // ---- QK^T: S^T[key][q], one 32-key subtile ----
    f32x16 sT = z16;
    __builtin_amdgcn_s_setprio(1);
#pragma unroll
    for (int c = 0; c < 4; ++c)
      sT = mfma32(kf[c], qf[c], sT);
    __builtin_amdgcn_s_setprio(0);

    // ---- p = exp2(raw score); bounded, no max needed ----
#pragma unroll
    for (int i = 0; i < 16; ++i) sT[i] = __builtin_amdgcn_exp2f(sT[i]);

    // ---- denominator partials ----
#pragma unroll
    for (int i = 0; i < 4; ++i)
      l4[i] += (sT[i] + sT[i + 4]) + (sT[i + 8] + sT[i + 12]);

    // ---- pack P B-frags, then 4-MFMA PV cluster ----
    bf16x8 pfr[2];
#pragma unroll
    for (int kc = 0; kc < 2; ++kc) {
      const int bix = kc * 8;
      uint4 bw;
      bw.x = pkc(sT[bix + 0], sT[bix + 1]);
      bw.y = pkc(sT[bix + 2], sT[bix + 3]);
      bw.z = pkc(sT[bix + 4], sT[bix + 5]);
      bw.w = pkc(sT[bix + 6], sT[bix + 7]);
      pfr[kc] = as_bf(bw);
    }
    __builtin_amdgcn_s_setprio(1);
#pragma unroll
    for (int kc = 0; kc < 2; ++kc) {
      acc[0] = mfma32(vf2[0][kc], pfr[kc], acc[0]);
      acc[1] = mfma32(vf2[1][kc], pfr[kc], acc[1]);
    }
    __builtin_amdgcn_s_setprio(0);
  }

  float lrun = (l4[0] + l4[1]) + (l4[2] + l4[3]);
  // per-half full denominator (own hi-half + partner)
  float lhalf = lrun + __shfl_xor(lrun, 32);

  // ---- flash-combine of the two KV halves via LDS (plain add; no max) ----
  __syncthreads();
  float* shm = (float*)smem;
  if (hf == 1) {
    float* ab = shm + qw * 2048;   // [64 d][32 q]
#pragma unroll
    for (int dt = 0; dt < 2; ++dt)
#pragma unroll
      for (int i = 0; i < 16; ++i) {
        int d = (i & 3) + 8 * (i >> 2) + 4 * hi + 32 * dt;
        ab[d * 32 + li] = acc[dt][i];
      }
    if (hi == 0) shm[8192 + qw * 32 + li] = lhalf;
  }
  __syncthreads();
  if (hf == 0) {
    float* ab = shm + qw * 2048;
    float l1 = shm[8192 + qw * 32 + li];
    float linv = 1.0f / (lhalf + l1);
#pragma unroll
    for (int dt = 0; dt < 2; ++dt)
#pragma unroll
      for (int i = 0; i < 16; ++i) {
        int d = (i & 3) + 8 * (i >> 2) + 4 * hi + 32 * dt;
        acc[dt][i] = (acc[dt][i] + ab[d * 32 + li]) * linv;
      }
    __asm__ volatile("" ::: "memory");

    // ---- epilogue: transpose via LDS (wave-private region), coalesced stores ----
    float* eb = shm + qw * 2048;   // [32 q][33 d-pad] floats
#pragma unroll
    for (int dt = 0; dt < 2; ++dt) {
#pragma unroll
      for (int i = 0; i < 16; ++i)
        eb[li * 33 + ((i & 3) + 8 * (i >> 2) + 4 * hi)] = acc[dt][i];
      __asm__ volatile("" ::: "memory");
#pragma unroll
      for (int it = 0; it < 16; ++it) {
        int q = it * 2 + hi;
        float v = eb[q * 33 + li];
        out[(size_t)(q0 + q) * 1024 + h * 64 + dt * 32 + li] = v;
      }
      __asm__ volatile("" ::: "memory");
    }
  }
}

extern "C" void kernel_launch(void* const* d_in, const int* in_sizes, int n_in,
                              void* d_out, int out_size, void* d_ws, size_t ws_size,
                              hipStream_t stream) {
  const float* x  = (const float*)d_in[0];
  const float* wq = (const float*)d_in[1];
  const float* wk = (const float*)d_in[2];
  const float* wv = (const float*)d_in[3];
  float* out = (float*)d_out;
  char* ws = (char*)d_ws;

  unsigned short* qbf = (unsigned short*)(ws);
  unsigned short* KF  = (unsigned short*)(ws + ((size_t)8 << 20));
  unsigned short* VF  = (unsigned short*)(ws + ((size_t)16 << 20));
  unsigned short* xbf = (unsigned short*)(ws + ((size_t)24 << 20));
  unsigned short* wbf = (unsigned short*)(ws + ((size_t)32 << 20));
  float2* ctst = (float2*)(ws + ((size_t)38 << 20));

  k_prep<<<dim3(7680), dim3(256), 0, stream>>>(x, wq, wk, wv, xbf, wbf, ctst);
  k_gemm<<<dim3(24, 32), dim3(256), 0, stream>>>(xbf, wbf, ctst, qbf, KF, VF);
  k_attn<<<dim3(512), dim3(512), 0, stream>>>(qbf, KF, VF, out);
}

// Round 21
// 149.076 us; speedup vs baseline: 1.1032x; 1.1032x over previous
//
#include <hip/hip_runtime.h>
#include <stdint.h>

// RoPE attention, MI355X. S=4096, HID=1024, 16 heads x 64.
// R21 = total-best R13 config (LDS-staged KVBLK=32 attn @101us, cheap row-major
// kbf + transposed vT epilogue) + two individually-proven non-attn wins:
// gll16 double-buffered gemm staging (R19/20 loop) and fused prep with
// interleaved (cos,sin) float2 table (R20). Fragment-linear K/V dropped: its
// ~3us attn gain cost 12+us in the gemm epilogue (R14-R20 ledger).
// ws layout: qbf 8MB | kbf 8MB | vT 8MB | xbf 8MB | wbf 6MB | ctst 1MB

#define SEQLEN 4096
#define NHEAD 16
#define HDIM 64

typedef __bf16 bf16x8 __attribute__((ext_vector_type(8)));
typedef float f32x4 __attribute__((ext_vector_type(4)));
typedef float f32x16 __attribute__((ext_vector_type(16)));

__device__ __forceinline__ unsigned short f2bf(float f) {
  union { float f; unsigned int u; } v; v.f = f;
  unsigned int r = v.u + 0x7FFFu + ((v.u >> 16) & 1u);
  return (unsigned short)(r >> 16);
}
__device__ __forceinline__ unsigned int pkc(float lo, float hi) {
  union { __bf16 b[2]; unsigned int u; } z;
  z.b[0] = (__bf16)lo; z.b[1] = (__bf16)hi;
  return z.u;
}
__device__ __forceinline__ bf16x8 as_bf(uint4 v) { return __builtin_bit_cast(bf16x8, v); }
__device__ __forceinline__ f32x4 mfma16(bf16x8 a, bf16x8 b, f32x4 c) {
  return __builtin_amdgcn_mfma_f32_16x16x32_bf16(a, b, c, 0, 0, 0);
}
__device__ __forceinline__ f32x16 mfma32(bf16x8 a, bf16x8 b, f32x16 c) {
  return __builtin_amdgcn_mfma_f32_32x32x16_bf16(a, b, c, 0, 0, 0);
}
__device__ __forceinline__ uint2 mku2(unsigned x, unsigned y) {
  uint2 r; r.x = x; r.y = y; return r;
}
__device__ __forceinline__ void gll16(const void* g, void* l) {
  __builtin_amdgcn_global_load_lds(
      (const __attribute__((address_space(1))) void*)g,
      (__attribute__((address_space(3))) void*)l, 16, 0, 0);
}

// ---------------- prep: fp32->bf16 convert (x, wq|wk|wv) + RoPE float2 table ----
__global__ __launch_bounds__(256) void k_prep(
    const float* __restrict__ x, const float* __restrict__ wq,
    const float* __restrict__ wk, const float* __restrict__ wv,
    unsigned short* __restrict__ xbf, unsigned short* __restrict__ wbf,
    float2* __restrict__ ctst) {
  const int NX = SEQLEN * 1024 / 4;         // 1048576 float4s
  const int NW = 1024 * 1024 / 4;           // 262144 (pow2)
  if (blockIdx.x < 7168) {
    int i = blockIdx.x * 256 + threadIdx.x;
    float4 v;
    unsigned short* dst;
    int di;
    if (i < NX) {
      v = ((const float4*)x)[i]; dst = xbf; di = i;
    } else {
      int j = i - NX;
      const float4* src = (const float4*)((j < NW) ? wq : (j < 2 * NW) ? wk : wv);
      v = src[j & (NW - 1)];
      dst = wbf; di = j;
    }
    ushort4 o; o.x = f2bf(v.x); o.y = f2bf(v.y); o.z = f2bf(v.z); o.w = f2bf(v.w);
    ((ushort4*)dst)[di] = o;
  } else {
    int i = (blockIdx.x - 7168) * 256 + threadIdx.x;   // 4096*32 entries
    int s = i >> 5, j = i & 31;
    double inv = exp(-(double)j * 0.28782313662425572);  // ln(10000)/32
    double a = (double)s * inv;
    float2 cs; cs.x = (float)cos(a); cs.y = (float)sin(a);
    ctst[i] = cs;
  }
}

// ---------------- QKV GEMM (gll16 staging + R13 cheap epilogue) ----------------
// C[4096][3072] = Xbf[4096][1024] * Wbf[3072][1024]^T. 128x128 tile, BK=32,
// 4 waves (2x2 of 64x64). Staging: 4 global_load_lds(16B/lane)/wave/K-step into
// linear [128][64B] LDS, double-buffered, ONE barrier per K-step (m97 structure).
// Epilogue: RoPE; Q/K -> row-major qbf/kbf (2B stores), V -> transposed vT[h][d][s].
__global__ __launch_bounds__(256) void k_gemm(
    const unsigned short* __restrict__ xbf, const unsigned short* __restrict__ wbf,
    const float2* __restrict__ ctst,
    unsigned short* __restrict__ qbf, unsigned short* __restrict__ kbf,
    unsigned short* __restrict__ vT) {
  __shared__ __align__(16) unsigned short As[2][128 * 32];  // 8KB per buffer
  __shared__ __align__(16) unsigned short Bs[2][128 * 32];
  const int t = threadIdx.x;
  const int bn = blockIdx.x, bm = blockIdx.y;
  const int lane = t & 63, wave = t >> 6;
  const int r = lane & 15, g = lane >> 4;
  const int wm = wave >> 1, wn = wave & 1;

  // staging chunks: wave w covers rows [32w..32w+32); 4 lanes per 64B row
  const int c0 = 2 * wave, c1 = 2 * wave + 1;
  const int srowA = lane >> 2, sb = (lane & 3) * 16;
  const char* gA0 = (const char*)xbf + (size_t)(bm * 128 + 16 * c0 + srowA) * 2048 + sb;
  const char* gA1 = (const char*)xbf + (size_t)(bm * 128 + 16 * c1 + srowA) * 2048 + sb;
  const char* gB0 = (const char*)wbf + (size_t)(bn * 128 + 16 * c0 + srowA) * 2048 + sb;
  const char* gB1 = (const char*)wbf + (size_t)(bn * 128 + 16 * c1 + srowA) * 2048 + sb;

  // prologue: tile 0 -> buffer 0
  gll16(gA0, (char*)As[0] + c0 * 1024);
  gll16(gA1, (char*)As[0] + c1 * 1024);
  gll16(gB0, (char*)Bs[0] + c0 * 1024);
  gll16(gB1, (char*)Bs[0] + c1 * 1024);
  gA0 += 64; gA1 += 64; gB0 += 64; gB1 += 64;

  f32x4 zero4 = {0.f, 0.f, 0.f, 0.f};
  f32x4 acc[4][4];
#pragma unroll
  for (int m = 0; m < 4; ++m)
#pragma unroll
    for (int n = 0; n < 4; ++n) acc[m][n] = zero4;

  for (int kk = 0; kk < 32; ++kk) {
    __syncthreads();   // drains tile-kk loads + prior LDS reads
    if (kk < 31) {
      char* Ad = (char*)As[(kk + 1) & 1];
      char* Bd = (char*)Bs[(kk + 1) & 1];
      gll16(gA0, Ad + c0 * 1024);
      gll16(gA1, Ad + c1 * 1024);
      gll16(gB0, Bd + c0 * 1024);
      gll16(gB1, Bd + c1 * 1024);
      gA0 += 64; gA1 += 64; gB0 += 64; gB1 += 64;
    }
    const char* Ac = (const char*)As[kk & 1];
    const char* Bc = (const char*)Bs[kk & 1];
    bf16x8 af[4], bfr[4];
#pragma unroll
    for (int m = 0; m < 4; ++m)
      af[m] = as_bf(*(const uint4*)(Ac + (wm * 64 + m * 16 + r) * 64 + g * 16));
#pragma unroll
    for (int n = 0; n < 4; ++n)
      bfr[n] = as_bf(*(const uint4*)(Bc + (wn * 64 + n * 16 + r) * 64 + g * 16));
#pragma unroll
    for (int m = 0; m < 4; ++m)
#pragma unroll
      for (int n = 0; n < 4; ++n)
        acc[m][n] = mfma16(af[m], bfr[n], acc[m][n]);
  }

  // Epilogue (R13). C/D layout: col = lane&15 (=r), row = 4*g + reg.
  const int matid = bn >> 3;  // 0=q, 1=k, 2=v
#pragma unroll
  for (int m = 0; m < 4; ++m) {
    const int row0 = bm * 128 + wm * 64 + m * 16 + 4 * g;
#pragma unroll
    for (int n = 0; n < 4; ++n) {
      const int col = bn * 128 + wn * 64 + n * 16 + r;
      const int d = col & 63;
      const int hh = (col >> 6) & 15;
      if (matid < 2) {
        const int jdx = (col >> 1) & 31;
        const float sgn = (col & 1) ? 1.0f : -1.0f;
        unsigned short* dst = (matid == 0) ? qbf : kbf;
        // fold (1/8)*log2(e) into Q so attention works in exp2 domain
        const float qs = (matid == 0) ? 0.18033688011112042f : 1.0f;
#pragma unroll
        for (int j = 0; j < 4; ++j) {
          float v = acc[m][n][j];
          float p = __shfl_xor(v, 1);  // RoPE pair partner (col^1)
          int srow = row0 + j;
          float2 cs = ctst[srow * 32 + jdx];
          float o = (v * cs.x + p * cs.y * sgn) * qs;
          dst[(size_t)srow * 1024 + (hh * 64 + d)] = f2bf(o);
        }
      } else {
        // V stored transposed: vT[h][d][s]
        ushort4 o;
        o.x = f2bf(acc[m][n][0]); o.y = f2bf(acc[m][n][1]);
        o.z = f2bf(acc[m][n][2]); o.w = f2bf(acc[m][n][3]);
        *(ushort4*)&vT[((size_t)(hh * 64 + d)) * SEQLEN + row0] = o;
      }
    }
  }
}

// ---------------- Flash attention (R13 verbatim: KVBLK=32, b64-swizzled LDS,
//                  no-max exp2 softmax, sigma-PV, VALU denominator) ----------------
__global__ __launch_bounds__(512) void k_attn(
    const unsigned short* __restrict__ qbf, const unsigned short* __restrict__ kbf,
    const unsigned short* __restrict__ vT, float* __restrict__ out) {
  __shared__ __align__(16) char smem[33280];  // 2 halves x (K0|K1|V0|V1 4KB) + combine
  const int t = threadIdx.x;
  // XCD swizzle: 512 blocks, 8 XCDs, 64 blocks/XCD -> 2 heads per XCD
  const int b = blockIdx.x;
  const int work = (b & 7) * 64 + (b >> 3);
  const int h = work >> 5;
  const int qb = work & 31;
  const int lane = t & 63, wave = t >> 6;
  const int qw = wave & 3, hf = wave >> 2;
  const int li = lane & 31, hi = lane >> 5;
  const int q0 = qb * 128 + qw * 32;
  const int HB = hf * 16384;   // this wave's LDS half

  // Q fragments (B-operand): lane holds q = q0+li, d = c*16 + hi*8 + j. Pre-scaled.
  bf16x8 qf[4];
#pragma unroll
  for (int c = 0; c < 4; ++c)
    qf[c] = as_bf(*(const uint4*)((const char*)qbf +
              (size_t)(q0 + li) * 2048 + h * 128 + c * 32 + hi * 16));

  f32x16 z16 = {0.f};
  f32x16 acc[2];            // O^T accum: d-tile dt, row=d, col=q
  acc[0] = z16; acc[1] = z16;
  float l4[4] = {0.f, 0.f, 0.f, 0.f};

  // ---- loop-invariant LDS read addresses ----
  // K [32 rows][16 b64 slots], slot = (4c + 2hi + b0) ^ (li&15)
  const int mmK = (li & 15) ^ (hi << 1);
  int kra[4];
#pragma unroll
  for (int c = 0; c < 4; ++c)
    kra[c] = HB + li * 128 + ((((4 * c) ^ mmK)) << 3);
  // V [32 rows][16 b64 slots], slot = (dt*8 + 4kc + hi) ^ (li&15); partner ^2
  const int mmV = (li & 15) ^ hi;
  int vra[2][2];
#pragma unroll
  for (int dt = 0; dt < 2; ++dt)
#pragma unroll
    for (int kc = 0; kc < 2; ++kc)
      vra[dt][kc] = HB + 8192 + li * 128 + ((((dt * 8 + 4 * kc) ^ mmV)) << 3);

  // ---- staging addresses: per half, 256 threads ----
  const int tt = t & 255;
  const int kr = tt >> 3, c8 = tt & 7;        // K: 32 rows x 128B, 16B/thread
  const int vd = tt >> 2, c4 = tt & 3;        // V: 64 d-rows x 64B, 16B/thread
  const int wka = HB + kr * 128 + ((((2 * c8) ^ (kr & 15))) << 3);
  const int wva = HB + 8192 + (vd & 31) * 128 +
                  (((((vd >> 5) * 8 + 2 * c4) ^ (vd & 15))) << 3);

  const char* pK = (const char*)kbf + h * 128 +
                   (size_t)(hf * 2048 + kr) * 2048 + c8 * 16;
  const char* pV = (const char*)vT + (size_t)h * HDIM * SEQLEN * 2 +
                   (size_t)vd * 8192 + hf * 4096 + c4 * 16;

  uint4 rk, rv;
#define LD_KV32                                       \
  rk = *(const uint4*)pK; rv = *(const uint4*)pV;     \
  pK += 32 * 2048; pV += 64;

  LD_KV32

#pragma unroll 2
  for (int j = 0; j < 64; ++j) {
    const int JB = (j & 1) * 4096;   // compile-time after unroll-2
    // ---- stage K,V tile: 4 b64 swizzled writes ----
    *(uint2*)(smem + (wka + JB)) = mku2(rk.x, rk.y);
    *(uint2*)(smem + ((wka ^ 8) + JB)) = mku2(rk.z, rk.w);
    *(uint2*)(smem + (wva + JB)) = mku2(rv.x, rv.y);
    *(uint2*)(smem + ((wva ^ 8) + JB)) = mku2(rv.z, rv.w);
    __syncthreads();
    if (j < 63) { LD_KV32 }

    // ---- QK^T: S^T[key][q], one 32-key subtile ----
    f32x16 sT = z16;
    __builtin_amdgcn_s_setprio(1);
#pragma unroll
    for (int c = 0; c < 4; ++c) {
      uint2 a0 = *(const uint2*)(smem + (kra[c] + JB));
      uint2 a1 = *(const uint2*)(smem + ((kra[c] ^ 8) + JB));
      uint4 ku; ku.x = a0.x; ku.y = a0.y; ku.z = a1.x; ku.w = a1.y;
      sT = mfma32(as_bf(ku), qf[c], sT);
    }
    __builtin_amdgcn_s_setprio(0);

    // ---- V A-frags (sigma order) ----
    bf16x8 vf[2][2];
#pragma unroll
    for (int dt = 0; dt < 2; ++dt)
#pragma unroll
      for (int kc = 0; kc < 2; ++kc) {
        uint2 lo = *(const uint2*)(smem + (vra[dt][kc] + JB));
        uint2 hi2 = *(const uint2*)(smem + ((vra[dt][kc] ^ 16) + JB));
        uint4 vv; vv.x = lo.x; vv.y = lo.y; vv.z = hi2.x; vv.w = hi2.y;
        vf[dt][kc] = as_bf(vv);
      }

    // ---- p = exp2(raw score); bounded, no max needed ----
#pragma unroll
    for (int i = 0; i < 16; ++i) sT[i] = __builtin_amdgcn_exp2f(sT[i]);

    // ---- denominator partials (4 accumulators) ----
#pragma unroll
    for (int i = 0; i < 4; ++i)
      l4[i] += (sT[i] + sT[i + 4]) + (sT[i + 8] + sT[i + 12]);

    // ---- pack P B-frags, then 4-MFMA PV cluster ----
    bf16x8 pfr[2];
#pragma unroll
    for (int kc = 0; kc < 2; ++kc) {
      const int bix = kc * 8;
      uint4 bw;
      bw.x = pkc(sT[bix + 0], sT[bix + 1]);
      bw.y = pkc(sT[bix + 2], sT[bix + 3]);
      bw.z = pkc(sT[bix + 4], sT[bix + 5]);
      bw.w = pkc(sT[bix + 6], sT[bix + 7]);
      pfr[kc] = as_bf(bw);
    }
    __builtin_amdgcn_s_setprio(1);
#pragma unroll
    for (int kc = 0; kc < 2; ++kc) {
      acc[0] = mfma32(vf[0][kc], pfr[kc], acc[0]);
      acc[1] = mfma32(vf[1][kc], pfr[kc], acc[1]);
    }
    __builtin_amdgcn_s_setprio(0);
  }

  float lrun = (l4[0] + l4[1]) + (l4[2] + l4[3]);
  // per-half full denominator (own hi-half + partner)
  float lhalf = lrun + __shfl_xor(lrun, 32);

  // ---- flash-combine of the two KV halves via LDS (plain add; no max) ----
  __syncthreads();
  float* shm = (float*)smem;
  if (hf == 1) {
    float* ab = shm + qw * 2048;   // [64 d][32 q]
#pragma unroll
    for (int dt = 0; dt < 2; ++dt)
#pragma unroll
      for (int i = 0; i < 16; ++i) {
        int d = (i & 3) + 8 * (i >> 2) + 4 * hi + 32 * dt;
        ab[d * 32 + li] = acc[dt][i];
      }
    if (hi == 0) shm[8192 + qw * 32 + li] = lhalf;
  }
  __syncthreads();
  if (hf == 0) {
    float* ab = shm + qw * 2048;
    float l1 = shm[8192 + qw * 32 + li];
    float linv = 1.0f / (lhalf + l1);
#pragma unroll
    for (int dt = 0; dt < 2; ++dt)
#pragma unroll
      for (int i = 0; i < 16; ++i) {
        int d = (i & 3) + 8 * (i >> 2) + 4 * hi + 32 * dt;
        acc[dt][i] = (acc[dt][i] + ab[d * 32 + li]) * linv;
      }
    __asm__ volatile("" ::: "memory");

    // ---- epilogue: transpose via LDS (wave-private region), coalesced stores ----
    float* eb = shm + qw * 2048;   // [32 q][33 d-pad] floats
#pragma unroll
    for (int dt = 0; dt < 2; ++dt) {
#pragma unroll
      for (int i = 0; i < 16; ++i)
        eb[li * 33 + ((i & 3) + 8 * (i >> 2) + 4 * hi)] = acc[dt][i];
      __asm__ volatile("" ::: "memory");
#pragma unroll
      for (int it = 0; it < 16; ++it) {
        int q = it * 2 + hi;
        float v = eb[q * 33 + li];
        out[(size_t)(q0 + q) * 1024 + h * 64 + dt * 32 + li] = v;
      }
      __asm__ volatile("" ::: "memory");
    }
  }
}

extern "C" void kernel_launch(void* const* d_in, const int* in_sizes, int n_in,
                              void* d_out, int out_size, void* d_ws, size_t ws_size,
                              hipStream_t stream) {
  const float* x  = (const float*)d_in[0];
  const float* wq = (const float*)d_in[1];
  const float* wk = (const float*)d_in[2];
  const float* wv = (const float*)d_in[3];
  float* out = (float*)d_out;
  char* ws = (char*)d_ws;

  unsigned short* qbf = (unsigned short*)(ws);
  unsigned short* kbf = (unsigned short*)(ws + ((size_t)8 << 20));
  unsigned short* vT  = (unsigned short*)(ws + ((size_t)16 << 20));
  unsigned short* xbf = (unsigned short*)(ws + ((size_t)24 << 20));
  unsigned short* wbf = (unsigned short*)(ws + ((size_t)32 << 20));
  float2* ctst = (float2*)(ws + ((size_t)38 << 20));

  k_prep<<<dim3(7680), dim3(256), 0, stream>>>(x, wq, wk, wv, xbf, wbf, ctst);
  k_gemm<<<dim3(24, 32), dim3(256), 0, stream>>>(xbf, wbf, ctst, qbf, kbf, vT);
  k_attn<<<dim3(512), dim3(512), 0, stream>>>(qbf, kbf, vT, out);
}